// Round 11
// baseline (771.192 us; speedup 1.0000x reference)
//
#include <hip/hip_runtime.h>
#include <math.h>

#define NN 20000      // nodes
#define NE 320000     // edges
#define NG 64         // graphs
#define IND 128
#define HIDD 256
#define NH 4
#define ED 5
#define NACT 8
#define NEG 0.2f
#define MAXDEG 64
#define NWAVES 8192   // 2048 blocks x 4 waves = 256 CU x 32 waves (full residency)

// ---------------- fp32 GEMM, 128x64 tile, BK=32, 8x4 per thread ----------------
// (R8-proven: launch_bounds(256,4) caps VGPR<=128 -> 4 waves/SIMD; float4 staging)
__global__ __launch_bounds__(256, 4) void gemm128x64(
    const float* __restrict__ A, const float* __restrict__ Bl,
    const float* __restrict__ Br, float* __restrict__ Cl, float* __restrict__ Cr,
    int M, int K, int Ncol)
{
    const float* B = blockIdx.z ? Br : Bl;
    float*       C = blockIdx.z ? Cr : Cl;
    __shared__ float As[32][129];
    __shared__ float Bs[32][64];
    int bm = blockIdx.x * 128, bn = blockIdx.y * 64;
    int tid = threadIdx.x;
    int tx = tid & 15, ty = tid >> 4;
    float acc[8][4] = {};
    for (int k0 = 0; k0 < K; k0 += 32) {
        #pragma unroll
        for (int t = 0; t < 4; ++t) {
            int idx = tid + t * 256;
            int r = idx >> 3;
            int c4 = (idx & 7) * 4;
            int gr = bm + r;
            float4 v = {0.f, 0.f, 0.f, 0.f};
            if (gr < M) v = *(const float4*)&A[(size_t)gr * K + k0 + c4];
            As[c4 + 0][r] = v.x;
            As[c4 + 1][r] = v.y;
            As[c4 + 2][r] = v.z;
            As[c4 + 3][r] = v.w;
        }
        #pragma unroll
        for (int t = 0; t < 2; ++t) {
            int idx = tid + t * 256;
            int r = idx >> 4;
            int c4 = (idx & 15) * 4;
            float4 v = *(const float4*)&B[(size_t)(k0 + r) * Ncol + bn + c4];
            *(float4*)&Bs[r][c4] = v;
        }
        __syncthreads();
        #pragma unroll
        for (int k = 0; k < 32; ++k) {
            float4 a0 = *(const float4*)&As[k][ty * 8];
            float4 a1 = *(const float4*)&As[k][ty * 8 + 4];
            float4 b0 = *(const float4*)&Bs[k][tx * 4];
            float a[8] = {a0.x, a0.y, a0.z, a0.w, a1.x, a1.y, a1.z, a1.w};
            float b[4] = {b0.x, b0.y, b0.z, b0.w};
            #pragma unroll
            for (int i = 0; i < 8; ++i)
                #pragma unroll
                for (int j = 0; j < 4; ++j)
                    acc[i][j] = fmaf(a[i], b[j], acc[i][j]);
        }
        __syncthreads();
    }
    #pragma unroll
    for (int i = 0; i < 8; ++i) {
        int r = bm + ty * 8 + i;
        if (r < M) {
            float4 v = {acc[i][0], acc[i][1], acc[i][2], acc[i][3]};
            *(float4*)&C[(size_t)r * Ncol + bn + tx * 4] = v;
        }
    }
}

// ---------------- inverse adjacency: per-dst fixed slots ----------------
__global__ __launch_bounds__(256) void build_slots(const int* __restrict__ dst,
    int* __restrict__ deg, int* __restrict__ slots)
{
    int e = blockIdx.x * 256 + threadIdx.x;
    if (e >= NE) return;
    int d = dst[e];
    int pos = atomicAdd(&deg[d], 1);
    if (pos < MAXDEG) slots[d * MAXDEG + pos] = e;
}

// ---------------- FUSED layer, persistent waves + ticket balancing ----------------
// Wave processes node waveGid first (static), then pops nodes 8192.. from global ticket.
// Per-node arithmetic order identical to R5 (sequential slots; paired loads issued early).
template <int HEADS_T>
__global__ __launch_bounds__(256) void fused_agg(
    const int* __restrict__ deg, const int* __restrict__ slots,
    const int* __restrict__ src, const float* __restrict__ eattr,
    const float* __restrict__ xl, const float* __restrict__ xr,
    const float* __restrict__ We, const float* __restrict__ attw,
    const float* __restrict__ bias, float* __restrict__ out,
    int* __restrict__ tick)
{
    __shared__ float sWe[ED * HIDD];
    __shared__ float sAtt[HIDD];
    for (int i = threadIdx.x; i < ED * HIDD; i += 256) sWe[i] = We[i];
    for (int i = threadIdx.x; i < HIDD; i += 256) sAtt[i] = attw[i];
    __syncthreads();

    int wave = threadIdx.x >> 6, lane = threadIdx.x & 63;
    int c0 = lane * 4;

    float attr_[4], wer[ED][4];
    #pragma unroll
    for (int j = 0; j < 4; ++j) attr_[j] = sAtt[c0 + j];
    #pragma unroll
    for (int k = 0; k < ED; ++k)
        #pragma unroll
        for (int j = 0; j < 4; ++j) wer[k][j] = sWe[k * HIDD + c0 + j];

    int n = blockIdx.x * 4 + wave;   // static first node (0..8191)
    while (n < NN) {
        int dg = min(deg[n], MAXDEG);
        const int* slotrow = slots + (size_t)n * MAXDEG;

        float4 xr4 = *(const float4*)(xr + (size_t)n * HIDD + c0);
        float xra[4] = {xr4.x, xr4.y, xr4.z, xr4.w};

        float denom = 0.f;
        float acc[4] = {0.f, 0.f, 0.f, 0.f};

        int i = 0;
        for (; i + 2 <= dg; i += 2) {
            // issue both edges' loads before either compute (2x MLP on the chain)
            int eA = slotrow[i], eB = slotrow[i + 1];
            int sA = src[eA], sB = src[eB];
            float4 xA4 = *(const float4*)(xl + (size_t)sA * HIDD + c0);
            float4 xB4 = *(const float4*)(xl + (size_t)sB * HIDD + c0);
            float eaA[ED], eaB[ED];
            #pragma unroll
            for (int k = 0; k < ED; ++k) {
                eaA[k] = eattr[(size_t)eA * ED + k];
                eaB[k] = eattr[(size_t)eB * ED + k];
            }
            float xlA[4] = {xA4.x, xA4.y, xA4.z, xA4.w};
            float xlB[4] = {xB4.x, xB4.y, xB4.z, xB4.w};
            float pA = 0.f, pB = 0.f;
            #pragma unroll
            for (int j = 0; j < 4; ++j) {
                float evA = 0.f, evB = 0.f;
                #pragma unroll
                for (int k = 0; k < ED; ++k) {
                    evA = fmaf(eaA[k], wer[k][j], evA);
                    evB = fmaf(eaB[k], wer[k][j], evB);
                }
                float mA = xlA[j] + xra[j] + evA;
                float mB = xlB[j] + xra[j] + evB;
                mA = mA > 0.f ? mA : NEG * mA;
                mB = mB > 0.f ? mB : NEG * mB;
                pA = fmaf(mA, attr_[j], pA);
                pB = fmaf(mB, attr_[j], pB);
            }
            if (HEADS_T == 4) {
                #pragma unroll
                for (int off = 1; off < 16; off <<= 1) {
                    pA += __shfl_xor(pA, off, 64);
                    pB += __shfl_xor(pB, off, 64);
                }
            } else {
                #pragma unroll
                for (int off = 1; off < 64; off <<= 1) {
                    pA += __shfl_xor(pA, off, 64);
                    pB += __shfl_xor(pB, off, 64);
                }
            }
            float exA = expf(pA);
            float exB = expf(pB);
            denom += exA;               // same order as sequential loop
            denom += exB;
            #pragma unroll
            for (int j = 0; j < 4; ++j) acc[j] = fmaf(exA, xlA[j], acc[j]);
            #pragma unroll
            for (int j = 0; j < 4; ++j) acc[j] = fmaf(exB, xlB[j], acc[j]);
        }
        if (i < dg) {
            int eA = slotrow[i];
            int sA = src[eA];
            float4 xA4 = *(const float4*)(xl + (size_t)sA * HIDD + c0);
            float xlA[4] = {xA4.x, xA4.y, xA4.z, xA4.w};
            float eaA[ED];
            #pragma unroll
            for (int k = 0; k < ED; ++k) eaA[k] = eattr[(size_t)eA * ED + k];
            float pA = 0.f;
            #pragma unroll
            for (int j = 0; j < 4; ++j) {
                float evA = 0.f;
                #pragma unroll
                for (int k = 0; k < ED; ++k) evA = fmaf(eaA[k], wer[k][j], evA);
                float mA = xlA[j] + xra[j] + evA;
                mA = mA > 0.f ? mA : NEG * mA;
                pA = fmaf(mA, attr_[j], pA);
            }
            if (HEADS_T == 4) {
                #pragma unroll
                for (int off = 1; off < 16; off <<= 1) pA += __shfl_xor(pA, off, 64);
            } else {
                #pragma unroll
                for (int off = 1; off < 64; off <<= 1) pA += __shfl_xor(pA, off, 64);
            }
            float exA = expf(pA);
            denom += exA;
            #pragma unroll
            for (int j = 0; j < 4; ++j) acc[j] = fmaf(exA, xlA[j], acc[j]);
        }

        float inv = 1.f / (denom + 1e-16f);
        float4 o;
        o.x = fmaxf(acc[0] * inv + bias[c0 + 0], 0.f);
        o.y = fmaxf(acc[1] * inv + bias[c0 + 1], 0.f);
        o.z = fmaxf(acc[2] * inv + bias[c0 + 2], 0.f);
        o.w = fmaxf(acc[3] * inv + bias[c0 + 3], 0.f);
        *(float4*)(out + (size_t)n * HIDD + c0) = o;

        // pop next node (dynamic phase starts at NWAVES)
        int k = 0;
        if (lane == 0) k = atomicAdd(tick, 1);
        n = NWAVES + __shfl(k, 0, 64);
    }
}

// ---------------- global mean pool (batch is sorted) ----------------
#define POOL_CHUNK 128
__global__ __launch_bounds__(256) void pool_kernel(
    const float* __restrict__ h, const int* __restrict__ batch,
    float* __restrict__ pool, float* __restrict__ cnt)
{
    int c = threadIdx.x;
    int start = blockIdx.x * POOL_CHUNK;
    int end = min(start + POOL_CHUNK, NN);
    if (start >= NN) return;
    float acc = 0.f;
    int cur = batch[start];
    int localCount = 0;
    for (int n = start; n < end; ++n) {
        int g = batch[n];
        if (g != cur) {
            atomicAdd(&pool[cur * HIDD + c], acc);
            if (c == 0) atomicAdd(&cnt[cur], (float)localCount);
            acc = 0.f; localCount = 0; cur = g;
        }
        acc += h[(size_t)n * HIDD + c];
        ++localCount;
    }
    atomicAdd(&pool[cur * HIDD + c], acc);
    if (c == 0) atomicAdd(&cnt[cur], (float)localCount);
}

// ---------------- heads: logits [G,8] and value [G], out [G,9] ----------------
__global__ __launch_bounds__(256) void head_kernel(
    const float* __restrict__ pool, const float* __restrict__ cnt,
    const float* __restrict__ Wp, const float* __restrict__ bp,
    const float* __restrict__ Wv, const float* __restrict__ bv,
    float* __restrict__ out)
{
    int g = blockIdx.x;
    int c = threadIdx.x;
    float gv = pool[g * HIDD + c] / fmaxf(cnt[g], 1.0f);
    __shared__ float red[256];
    for (int j = 0; j < NACT + 1; ++j) {
        float w = (j < NACT) ? Wp[c * NACT + j] : Wv[c];
        red[c] = gv * w;
        __syncthreads();
        for (int sl = 128; sl > 0; sl >>= 1) {
            if (c < sl) red[c] += red[c + sl];
            __syncthreads();
        }
        if (c == 0) out[g * (NACT + 1) + j] = red[0] + ((j < NACT) ? bp[j] : bv[0]);
        __syncthreads();
    }
}

extern "C" void kernel_launch(void* const* d_in, const int* in_sizes, int n_in,
                              void* d_out, int out_size, void* d_ws, size_t ws_size,
                              hipStream_t stream)
{
    const float* x    = (const float*)d_in[0];
    const int*   ei   = (const int*)d_in[1];
    const int*   batch= (const int*)d_in[2];
    const float* ea   = (const float*)d_in[3];
    const float* W1l  = (const float*)d_in[4];
    const float* W1r  = (const float*)d_in[5];
    const float* W1e  = (const float*)d_in[6];
    const float* att1 = (const float*)d_in[7];
    const float* b1   = (const float*)d_in[8];
    const float* W2l  = (const float*)d_in[9];
    const float* W2r  = (const float*)d_in[10];
    const float* W2e  = (const float*)d_in[11];
    const float* att2 = (const float*)d_in[12];
    const float* b2   = (const float*)d_in[13];
    const float* Wp   = (const float*)d_in[14];
    const float* bp   = (const float*)d_in[15];
    const float* Wv   = (const float*)d_in[16];
    const float* bv   = (const float*)d_in[17];
    const int* src = ei;
    const int* dst = ei + NE;
    float* out = (float*)d_out;

    // workspace layout (floats)
    float* ws = (float*)d_ws;
    size_t off = 0;
    float* A     = ws + off; off += (size_t)NN * HIDD;   // xl (layer 1 then layer 2)
    float* B     = ws + off; off += (size_t)NN * HIDD;   // xr (layer 1 then layer 2)
    float* C     = ws + off; off += (size_t)NN * HIDD;   // h1
    float* D     = ws + off; off += (size_t)NN * HIDD;   // h2
    float* pool  = ws + off; off += (size_t)NG * HIDD;
    float* cnt   = ws + off; off += NG;
    int*   tick1 = (int*)(ws + off); off += 2;           // ticket counters (zeroed)
    int*   tick2 = tick1 + 1;
    float* _pad  = ws + off; off += 2;                   // keep 16B alignment
    int*   deg   = (int*)(ws + off); off += NN;
    int*   slots = (int*)(ws + off); off += (size_t)NN * MAXDEG;
    (void)_pad;

    // zero: pool, cnt, ticks, pad, deg (contiguous region)
    hipMemsetAsync(pool, 0, (size_t)(NG * HIDD + NG + 4 + NN) * sizeof(float), stream);

    // inverse adjacency
    build_slots<<<(NE + 255) / 256, 256, 0, stream>>>(dst, deg, slots);

    // ---- layer 1 ----
    dim3 g1((NN + 127) / 128, HIDD / 64, 2);
    gemm128x64<<<g1, 256, 0, stream>>>(x, W1l, W1r, A, B, NN, IND, HIDD);
    fused_agg<4><<<NWAVES / 4, 256, 0, stream>>>(deg, slots, src, ea, A, B, W1e, att1, b1, C, tick1);

    // ---- layer 2 ----
    gemm128x64<<<g1, 256, 0, stream>>>(C, W2l, W2r, A, B, NN, HIDD, HIDD);
    fused_agg<1><<<NWAVES / 4, 256, 0, stream>>>(deg, slots, src, ea, A, B, W2e, att2, b2, D, tick2);

    // ---- pool + heads ----
    pool_kernel<<<(NN + POOL_CHUNK - 1) / POOL_CHUNK, 256, 0, stream>>>(D, batch, pool, cnt);
    head_kernel<<<NG, 256, 0, stream>>>(pool, cnt, Wp, bp, Wv, bv, out);
}

// Round 12
// 409.800 us; speedup vs baseline: 1.8819x; 1.8819x over previous
//
#include <hip/hip_runtime.h>
#include <math.h>

#define NN 20000      // nodes
#define NE 320000     // edges
#define NG 64         // graphs
#define IND 128
#define HIDD 256
#define NH 4
#define ED 5
#define NACT 8
#define NEG 0.2f
#define MAXDEG 64

// ---------------- fp32 GEMM, 128x64 tile, BK=32, 8x4 per thread ----------------
// (R8-proven: launch_bounds(256,4) caps VGPR<=128 -> 4 waves/SIMD; float4 staging)
__global__ __launch_bounds__(256, 4) void gemm128x64(
    const float* __restrict__ A, const float* __restrict__ Bl,
    const float* __restrict__ Br, float* __restrict__ Cl, float* __restrict__ Cr,
    int M, int K, int Ncol)
{
    const float* B = blockIdx.z ? Br : Bl;
    float*       C = blockIdx.z ? Cr : Cl;
    __shared__ float As[32][129];
    __shared__ float Bs[32][64];
    int bm = blockIdx.x * 128, bn = blockIdx.y * 64;
    int tid = threadIdx.x;
    int tx = tid & 15, ty = tid >> 4;
    float acc[8][4] = {};
    for (int k0 = 0; k0 < K; k0 += 32) {
        #pragma unroll
        for (int t = 0; t < 4; ++t) {
            int idx = tid + t * 256;
            int r = idx >> 3;
            int c4 = (idx & 7) * 4;
            int gr = bm + r;
            float4 v = {0.f, 0.f, 0.f, 0.f};
            if (gr < M) v = *(const float4*)&A[(size_t)gr * K + k0 + c4];
            As[c4 + 0][r] = v.x;
            As[c4 + 1][r] = v.y;
            As[c4 + 2][r] = v.z;
            As[c4 + 3][r] = v.w;
        }
        #pragma unroll
        for (int t = 0; t < 2; ++t) {
            int idx = tid + t * 256;
            int r = idx >> 4;
            int c4 = (idx & 15) * 4;
            float4 v = *(const float4*)&B[(size_t)(k0 + r) * Ncol + bn + c4];
            *(float4*)&Bs[r][c4] = v;
        }
        __syncthreads();
        #pragma unroll
        for (int k = 0; k < 32; ++k) {
            float4 a0 = *(const float4*)&As[k][ty * 8];
            float4 a1 = *(const float4*)&As[k][ty * 8 + 4];
            float4 b0 = *(const float4*)&Bs[k][tx * 4];
            float a[8] = {a0.x, a0.y, a0.z, a0.w, a1.x, a1.y, a1.z, a1.w};
            float b[4] = {b0.x, b0.y, b0.z, b0.w};
            #pragma unroll
            for (int i = 0; i < 8; ++i)
                #pragma unroll
                for (int j = 0; j < 4; ++j)
                    acc[i][j] = fmaf(a[i], b[j], acc[i][j]);
        }
        __syncthreads();
    }
    #pragma unroll
    for (int i = 0; i < 8; ++i) {
        int r = bm + ty * 8 + i;
        if (r < M) {
            float4 v = {acc[i][0], acc[i][1], acc[i][2], acc[i][3]};
            *(float4*)&C[(size_t)r * Ncol + bn + tx * 4] = v;
        }
    }
}

// ---------------- inverse adjacency: per-dst fixed slots ----------------
__global__ __launch_bounds__(256) void build_slots(const int* __restrict__ dst,
    int* __restrict__ deg, int* __restrict__ slots)
{
    int e = blockIdx.x * 256 + threadIdx.x;
    if (e >= NE) return;
    int d = dst[e];
    int pos = atomicAdd(&deg[d], 1);
    if (pos < MAXDEG) slots[d * MAXDEG + pos] = e;
}

// ---------------- FUSED layer: one wave per block per node ----------------
// 64-thread blocks: per-node retirement (no max-of-4-waves granularity loss), no LDS,
// no __syncthreads. We/att read from global once per wave (L1/L2-resident tables).
// Per-node arithmetic identical to R5 -> absmax 0.0.
template <int HEADS_T>
__global__ __launch_bounds__(64) void fused_agg(
    const int* __restrict__ deg, const int* __restrict__ slots,
    const int* __restrict__ src, const float* __restrict__ eattr,
    const float* __restrict__ xl, const float* __restrict__ xr,
    const float* __restrict__ We, const float* __restrict__ attw,
    const float* __restrict__ bias, float* __restrict__ out)
{
    int lane = threadIdx.x;
    int n = blockIdx.x;
    int c0 = lane * 4;

    int dg = min(deg[n], MAXDEG);
    const int* slotrow = slots + (size_t)n * MAXDEG;

    // per-lane constants from global (tiny tables, cache-resident)
    float attr_[4], wer[ED][4];
    #pragma unroll
    for (int j = 0; j < 4; ++j) attr_[j] = attw[c0 + j];
    #pragma unroll
    for (int k = 0; k < ED; ++k)
        #pragma unroll
        for (int j = 0; j < 4; ++j) wer[k][j] = We[k * HIDD + c0 + j];

    float4 xr4 = *(const float4*)(xr + (size_t)n * HIDD + c0);
    float xra[4] = {xr4.x, xr4.y, xr4.z, xr4.w};

    float denom = 0.f;
    float acc[4] = {0.f, 0.f, 0.f, 0.f};

    for (int i = 0; i < dg; ++i) {
        int e = slotrow[i];
        int s = src[e];
        float4 xl4 = *(const float4*)(xl + (size_t)s * HIDD + c0);
        float xla[4] = {xl4.x, xl4.y, xl4.z, xl4.w};
        float ea[ED];
        #pragma unroll
        for (int k = 0; k < ED; ++k) ea[k] = eattr[(size_t)e * ED + k];
        float partial = 0.f;
        #pragma unroll
        for (int j = 0; j < 4; ++j) {
            float ev = 0.f;
            #pragma unroll
            for (int k = 0; k < ED; ++k) ev = fmaf(ea[k], wer[k][j], ev);
            float m = xla[j] + xra[j] + ev;
            m = m > 0.f ? m : NEG * m;
            partial = fmaf(m, attr_[j], partial);
        }
        if (HEADS_T == 4) {
            #pragma unroll
            for (int off = 1; off < 16; off <<= 1)
                partial += __shfl_xor(partial, off, 64);
        } else {
            #pragma unroll
            for (int off = 1; off < 64; off <<= 1)
                partial += __shfl_xor(partial, off, 64);
        }
        float ex = expf(partial);
        denom += ex;
        #pragma unroll
        for (int j = 0; j < 4; ++j) acc[j] = fmaf(ex, xla[j], acc[j]);
    }

    float inv = 1.f / (denom + 1e-16f);
    float4 o;
    o.x = fmaxf(acc[0] * inv + bias[c0 + 0], 0.f);
    o.y = fmaxf(acc[1] * inv + bias[c0 + 1], 0.f);
    o.z = fmaxf(acc[2] * inv + bias[c0 + 2], 0.f);
    o.w = fmaxf(acc[3] * inv + bias[c0 + 3], 0.f);
    *(float4*)(out + (size_t)n * HIDD + c0) = o;
}

// ---------------- global mean pool (batch is sorted) ----------------
#define POOL_CHUNK 128
__global__ __launch_bounds__(256) void pool_kernel(
    const float* __restrict__ h, const int* __restrict__ batch,
    float* __restrict__ pool, float* __restrict__ cnt)
{
    int c = threadIdx.x;
    int start = blockIdx.x * POOL_CHUNK;
    int end = min(start + POOL_CHUNK, NN);
    if (start >= NN) return;
    float acc = 0.f;
    int cur = batch[start];
    int localCount = 0;
    for (int n = start; n < end; ++n) {
        int g = batch[n];
        if (g != cur) {
            atomicAdd(&pool[cur * HIDD + c], acc);
            if (c == 0) atomicAdd(&cnt[cur], (float)localCount);
            acc = 0.f; localCount = 0; cur = g;
        }
        acc += h[(size_t)n * HIDD + c];
        ++localCount;
    }
    atomicAdd(&pool[cur * HIDD + c], acc);
    if (c == 0) atomicAdd(&cnt[cur], (float)localCount);
}

// ---------------- heads: logits [G,8] and value [G], out [G,9] ----------------
__global__ __launch_bounds__(256) void head_kernel(
    const float* __restrict__ pool, const float* __restrict__ cnt,
    const float* __restrict__ Wp, const float* __restrict__ bp,
    const float* __restrict__ Wv, const float* __restrict__ bv,
    float* __restrict__ out)
{
    int g = blockIdx.x;
    int c = threadIdx.x;
    float gv = pool[g * HIDD + c] / fmaxf(cnt[g], 1.0f);
    __shared__ float red[256];
    for (int j = 0; j < NACT + 1; ++j) {
        float w = (j < NACT) ? Wp[c * NACT + j] : Wv[c];
        red[c] = gv * w;
        __syncthreads();
        for (int sl = 128; sl > 0; sl >>= 1) {
            if (c < sl) red[c] += red[c + sl];
            __syncthreads();
        }
        if (c == 0) out[g * (NACT + 1) + j] = red[0] + ((j < NACT) ? bp[j] : bv[0]);
        __syncthreads();
    }
}

extern "C" void kernel_launch(void* const* d_in, const int* in_sizes, int n_in,
                              void* d_out, int out_size, void* d_ws, size_t ws_size,
                              hipStream_t stream)
{
    const float* x    = (const float*)d_in[0];
    const int*   ei   = (const int*)d_in[1];
    const int*   batch= (const int*)d_in[2];
    const float* ea   = (const float*)d_in[3];
    const float* W1l  = (const float*)d_in[4];
    const float* W1r  = (const float*)d_in[5];
    const float* W1e  = (const float*)d_in[6];
    const float* att1 = (const float*)d_in[7];
    const float* b1   = (const float*)d_in[8];
    const float* W2l  = (const float*)d_in[9];
    const float* W2r  = (const float*)d_in[10];
    const float* W2e  = (const float*)d_in[11];
    const float* att2 = (const float*)d_in[12];
    const float* b2   = (const float*)d_in[13];
    const float* Wp   = (const float*)d_in[14];
    const float* bp   = (const float*)d_in[15];
    const float* Wv   = (const float*)d_in[16];
    const float* bv   = (const float*)d_in[17];
    const int* src = ei;
    const int* dst = ei + NE;
    float* out = (float*)d_out;

    // workspace layout (floats)
    float* ws = (float*)d_ws;
    size_t off = 0;
    float* A     = ws + off; off += (size_t)NN * HIDD;   // xl (layer 1 then layer 2)
    float* B     = ws + off; off += (size_t)NN * HIDD;   // xr (layer 1 then layer 2)
    float* C     = ws + off; off += (size_t)NN * HIDD;   // h1
    float* D     = ws + off; off += (size_t)NN * HIDD;   // h2
    float* pool  = ws + off; off += (size_t)NG * HIDD;
    float* cnt   = ws + off; off += NG;
    int*   deg   = (int*)(ws + off); off += NN;
    int*   slots = (int*)(ws + off); off += (size_t)NN * MAXDEG;

    // zero: pool, cnt, deg (contiguous region)
    hipMemsetAsync(pool, 0, (size_t)(NG * HIDD + NG + NN) * sizeof(float), stream);

    // inverse adjacency
    build_slots<<<(NE + 255) / 256, 256, 0, stream>>>(dst, deg, slots);

    // ---- layer 1 ----
    dim3 g1((NN + 127) / 128, HIDD / 64, 2);
    gemm128x64<<<g1, 256, 0, stream>>>(x, W1l, W1r, A, B, NN, IND, HIDD);
    fused_agg<4><<<NN, 64, 0, stream>>>(deg, slots, src, ea, A, B, W1e, att1, b1, C);

    // ---- layer 2 ----
    gemm128x64<<<g1, 256, 0, stream>>>(C, W2l, W2r, A, B, NN, HIDD, HIDD);
    fused_agg<1><<<NN, 64, 0, stream>>>(deg, slots, src, ea, A, B, W2e, att2, b2, D);

    // ---- pool + heads ----
    pool_kernel<<<(NN + POOL_CHUNK - 1) / POOL_CHUNK, 256, 0, stream>>>(D, batch, pool, cnt);
    head_kernel<<<NG, 256, 0, stream>>>(pool, cnt, Wp, bp, Wv, bv, out);
}